// Round 6
// baseline (251.114 us; speedup 1.0000x reference)
//
#include <hip/hip_runtime.h>

// MovementEmbeddingModule: bs=4, d=16, K=10, C=3, h=w=128
// out: (4, 60, 16, 128, 128) f32; out[b][k*6+c][d][y][x]
//
// Grid-strided LINEAR-SWEEP writer: out is 61440 chunks of 4 KB
// (chunk j = (b,ch,d,sub): 8 rows x 128 cols of one output channel).
// 2048 resident blocks process chunks bid, bid+2048, ... so the aggregate
// store stream sweeps the 252 MB buffer in address order like the harness
// fill (6.7 TB/s) instead of 12K concurrent 1 MiB-strided streams (~2.7 TB/s).
#define BS 4
#define DD 16
#define KK 10
#define CC 3
#define HH 128
#define WW 128
#define HW   (HH*WW)            // 16384
#define CHW  (CC*HW)            // 49152
#define IMG_FLOATS (BS*CHW)     // 196608
#define PAD_FLOATS 24576        // 96 KB guard each side (covers +-66 KB excursion)
#define WS_NEED ((size_t)(IMG_FLOATS + 2*PAD_FLOATS) * 4)

#define NCH    (6*KK)                  // 60 output channels per batch
#define NCHUNK (BS*NCH*DD*16)          // 61440 4KB-chunks
#define NBLK   2048
#define CPB    (NCHUNK/NBLK)           // 30 chunks per block (exact)

using f4 = __attribute__((ext_vector_type(4))) float;

// 4-byte-aligned 16B chunk (source col base is icx+4*xg: dword- not 16B-aligned)
struct F4U { float v[4]; };

__global__ __launch_bounds__(256) void img_pad_copy(
    const float* __restrict__ img, float* __restrict__ dst)
{
    const int i = (int)(blockIdx.x * 256u + threadIdx.x) * 4;
    *(f4*)(dst + i) = *(const f4*)(img + i);
}

// PADDED: src = ws+PAD_FLOATS holds img with guard pads -> no clamping in the
// hot path (OOB elements are garbage, zeroed by NaN-safe selects).
// !PADDED fallback: per-element clamped scalar loads straight from img.
template<bool PADDED>
__global__ __launch_bounds__(256) void movement_embed_sweep(
    const float* __restrict__ kp_app,   // (4,1,10,2)
    const float* __restrict__ kp_vid,   // (4,16,10,2)
    const float* __restrict__ src,
    float* __restrict__ out)
{
    const int tid = (int)threadIdx.x;
    const int ly  = tid >> 5;               // local row 0..7
    const int x4  = (tid & 31) * 4;         // float4 column
    const float step = 2.0f / 127.0f;
    const float gx0  = (float)x4 * step - 1.0f;

    for (int j = (int)blockIdx.x; j < NCHUNK; j += NBLK) {
        // chunk decode (all block-uniform -> SALU)
        const int sub = j & 15;
        const int d   = (j >> 4) & 15;
        const unsigned bc = (unsigned)j >> 8;    // b*60 + ch, < 240
        const unsigned ch = bc % NCH;
        const unsigned b  = bc / NCH;
        const unsigned k  = ch / 6u;
        const unsigned c  = ch - k * 6u;

        const int y = sub * 8 + ly;

        // wave-uniform keypoint math (SGPR path)
        const float kvx  = kp_vid[((b*DD + d)*KK + k)*2 + 0];
        const float kvy  = kp_vid[((b*DD + d)*KK + k)*2 + 1];
        const float kv0x = kp_vid[((b*DD + 0)*KK + k)*2 + 0];
        const float kv0y = kp_vid[((b*DD + 0)*KK + k)*2 + 1];
        const float kax  = kp_app[(b*KK + k)*2 + 0];
        const float kay  = kp_app[(b*KK + k)*2 + 1];

        const float diffx = kvx - kv0x;     // exactly 0 at d==0
        const float diffy = kvy - kv0y;
        const float vdx = -diffx;           // kp_video_diff
        const float vdy = -diffy;

        f4 V;
        if (c == 0) {
            // heatmap: exp(-50*r^2(kp_mean)) - exp(-50*r^2(kp_app)); 0 at d==0
            const float mx = diffx + kax;
            const float my = diffy + kay;
            const float gy  = (float)y * step - 1.0f;
            const float dy1 = gy - my, dy0 = gy - kay;
            const float dy1sq = dy1 * dy1, dy0sq = dy0 * dy0;
            float hv[4];
#pragma unroll
            for (int e = 0; e < 4; ++e) {
                const float gx = gx0 + (float)e * step;
                const float dx1 = gx - mx, dx0 = gx - kax;
                hv[e] = __expf(-50.0f * (dx1 * dx1 + dy1sq))
                      - __expf(-50.0f * (dx0 * dx0 + dy0sq));
            }
            V.x = hv[0]; V.y = hv[1]; V.z = hv[2]; V.w = hv[3];
        } else if (c == 1) {
            V.x = vdx; V.y = vdx; V.z = vdx; V.w = vdx;
        } else if (c == 2) {
            V.x = vdy; V.y = vdy; V.z = vdy; V.w = vdy;
        } else {
            // deformed channel c-3: uniform bilinear (coord = pixel + const)
            const float cx = vdx * 63.5f;
            const float cy = vdy * 63.5f;
            const float fcx = floorf(cx), fcy = floorf(cy);
            const int icx = (int)fcx, icy = (int)fcy;
            const float wx1 = cx - fcx, wx0 = 1.0f - wx1;
            const float wy1 = cy - fcy, wy0 = 1.0f - wy1;

            const int r0   = y + icy;       // top source row (unclamped)
            const int col0 = icx + x4;      // left source col (unclamped)
            const bool rv0 = (unsigned)r0       < (unsigned)HH;
            const bool rv1 = (unsigned)(r0 + 1) < (unsigned)HH;

            float a0[5], a1[5];
            if constexpr (PADDED) {
                const long idx = (long)b * CHW + (long)(c - 3u) * HW
                               + (long)r0 * WW + (long)col0;
                const float* p = src + idx;     // may dip into guard pads: safe
                const F4U A  = *(const F4U*)p;
                const float a4 = p[4];
                const F4U Bt = *(const F4U*)(p + WW);
                const float b4 = p[WW + 4];
#pragma unroll
                for (int e = 0; e < 4; ++e) { a0[e] = A.v[e]; a1[e] = Bt.v[e]; }
                a0[4] = a4; a1[4] = b4;
            } else {
                const int rc0 = min(max(r0, 0), HH - 1);
                const int rc1 = min(max(r0 + 1, 0), HH - 1);
                const int cb  = (int)b * CHW + (int)(c - 3u) * HW;
#pragma unroll
                for (int e = 0; e < 5; ++e) {
                    const int cc = min(max(col0 + e, 0), WW - 1);
                    a0[e] = src[cb + rc0 * WW + cc];
                    a1[e] = src[cb + rc1 * WW + cc];
                }
            }
            // zero-padding masks (select, not multiply: pad garbage may be NaN)
#pragma unroll
            for (int e = 0; e < 5; ++e) {
                const bool cvv = (unsigned)(col0 + e) < (unsigned)WW;
                a0[e] = (rv0 && cvv) ? a0[e] : 0.0f;
                a1[e] = (rv1 && cvv) ? a1[e] : 0.0f;
            }
            float dv[4];
#pragma unroll
            for (int e = 0; e < 4; ++e) {
                const float h0 = wx0 * a0[e] + wx1 * a0[e + 1];
                const float h1 = wx0 * a1[e] + wx1 * a1[e + 1];
                dv[e] = wy0 * h0 + wy1 * h1;
            }
            V.x = dv[0]; V.y = dv[1]; V.z = dv[2]; V.w = dv[3];
        }

        // chunk-linear store: out + j*1024 floats + tid*4
        *(f4*)(out + ((size_t)(unsigned)j << 10) + (unsigned)(tid << 2)) = V;
    }
}

extern "C" void kernel_launch(void* const* d_in, const int* in_sizes, int n_in,
                              void* d_out, int out_size, void* d_ws, size_t ws_size,
                              hipStream_t stream) {
    const float* kp_app = (const float*)d_in[0];   // (4,1,10,2)
    const float* kp_vid = (const float*)d_in[1];   // (4,16,10,2)
    const float* img    = (const float*)d_in[2];   // (4,3,1,128,128)
    float* out = (float*)d_out;                    // (4,60,16,128,128)

    if (d_ws != nullptr && ws_size >= WS_NEED) {
        float* wimg = (float*)d_ws;
        img_pad_copy<<<IMG_FLOATS / (256 * 4), 256, 0, stream>>>(img, wimg + PAD_FLOATS);
        movement_embed_sweep<true><<<NBLK, 256, 0, stream>>>(
            kp_app, kp_vid, wimg + PAD_FLOATS, out);
    } else {
        movement_embed_sweep<false><<<NBLK, 256, 0, stream>>>(
            kp_app, kp_vid, img, out);
    }
}